// Round 9
// baseline (799.475 us; speedup 1.0000x reference)
//
#include <hip/hip_runtime.h>

// ---- types ----
typedef __bf16 bf16x8 __attribute__((ext_vector_type(8)));
typedef float  floatx4 __attribute__((ext_vector_type(4)));
typedef float  fvec4  __attribute__((ext_vector_type(4)));
typedef unsigned short ushort4v __attribute__((ext_vector_type(4)));

__device__ __forceinline__ unsigned short f2bf(float f) {
  unsigned int u = __float_as_uint(f);
  u = u + 0x7FFFu + ((u >> 16) & 1u);   // RNE
  return (unsigned short)(u >> 16);
}

__device__ __forceinline__ void gload_lds16(const unsigned short* g, unsigned short* l) {
  __builtin_amdgcn_global_load_lds(
      (const __attribute__((address_space(1))) unsigned int*)(g),
      (__attribute__((address_space(3))) unsigned int*)(l), 16, 0, 0);
}

// ws layout (u16-elem offsets unless noted):
//   0        : WP2 bf16 [29][256][512]
//   3801088  : WP3 bf16 [2][256][768]
//   8388608  : carriers l=0..15 (k-major swizzled, as R8):
//              carrier[l] input of layer l; l0..14: 16 x 65536 u16 (KW2),
//              carrier15: 16 x 49152 u16 (KW3) at 24117248.
//   90 MiB   : tbl u16 [2][64][128] (assemble)
//   96 MiB   : Y fp32 [31][16*256][128]
#define WP3_OFF   3801088
#define XC0_E     8388608
#define C15_E     24117248
#define TBL_E     47185920
#define Y_B       100663296

// ---- prep: bf16 weight copies + X0 carrier (k-major swizzled) ----
__global__ __launch_bounds__(256) void prep_kernel(
    const float* __restrict__ w2, const float* __restrict__ w3,
    const float* __restrict__ x, unsigned short* __restrict__ ws)
{
  int g = blockIdx.x * 256 + threadIdx.x;          // 0 .. 1179647
  if (g < 1048576) {
    const float* src; unsigned short* dst;
    if (g < 950272) { src = w2; dst = ws; }
    else            { g -= 950272; src = w3; dst = ws + WP3_OFF; }
    fvec4 v = *reinterpret_cast<const fvec4*>(src + 4 * g);
    ushort4v o;
    o[0] = f2bf(v[0]); o[1] = f2bf(v[1]); o[2] = f2bf(v[2]); o[3] = f2bf(v[3]);
    *reinterpret_cast<ushort4v*>(dst + 4 * g) = o;
  } else {
    const int h = g - 1048576;                     // 0..131071 over x float4 groups
    const long f = (long)4 * h;
    const int bb = (int)(f >> 15);
    const int i  = (int)((f >> 7) & 255);
    const int p0 = (int)(f & 127);
    fvec4 v = *reinterpret_cast<const fvec4*>(x + f);
    unsigned short* xb = ws + XC0_E + (long)bb * 65536;
#pragma unroll
    for (int j = 0; j < 4; ++j) {
      const int p = p0 + j;
      const unsigned short bf = f2bf(v[j]);
      xb[p * 512 + ((2 * i) ^ ((p & 7) << 3))] = bf;
      if (p >= 1) xb[(p - 1) * 512 + ((2 * i + 1) ^ (((p - 1) & 7) << 3))] = bf;
    }
  }
}

// ---- per-half assemble index table (validated R7/R8) ----
__global__ __launch_bounds__(256) void tbl_kernel(unsigned short* __restrict__ tbl)
{
  const int g = blockIdx.x * 256 + threadIdx.x;   // 0..16383
  const int h = g >> 13, rl = (g >> 7) & 63, c = g & 127;
  const int r = h * 64 + rl, d = c - r;
  unsigned short v = 0xFFFFu;
  if (d == 0) v = (unsigned short)(31 * 65 + rl);
  else if (d >= 1 && d <= 15) v = (unsigned short)((d - 1) * 65 + rl);
  else if (d >= 17 && d <= 31 && (d & 1) == 1 && (r & 1) == 0)
    v = (unsigned short)((15 + ((d - 17) >> 1)) * 65 + (rl >> 1));
  else if (d >= 35 && d <= 63 && (d & 3) == 3 && (r & 3) == 0)
    v = (unsigned short)((23 + ((d - 35) >> 2)) * 65 + (rl >> 2));
  tbl[g] = v;
}

// ---- conv layer (validated R8): k-major swizzled carriers, async staging ----
template<int KW, int KWN>
__global__ __launch_bounds__(256) void conv_kernel(
    const unsigned short* __restrict__ Xin, unsigned short* __restrict__ Xout,
    const unsigned short* __restrict__ WP, const float* __restrict__ bias,
    float* __restrict__ Yl, int Lout)
{
  constexpr int WROW  = 256 * KW;
  constexpr int BSTR  = (KW == 2) ? 65536 : 49152;
  constexpr int BSTRN = (KWN == 3) ? 49152 : 65536;
  constexpr int KS    = 256 * KW;
  constexpr int NLD   = (KW == 2) ? 8 : 12;
  __shared__ unsigned short LA[32 * WROW];

  const int tid = threadIdx.x, wave = tid >> 6, lane = tid & 63;
  const int b = blockIdx.z, m0 = blockIdx.x * 32, n0 = blockIdx.y * 64;
  {
    const unsigned short* src = Xin + (long)b * BSTR + (long)m0 * WROW
                              + wave * (NLD * 512) + lane * 8;
    unsigned short* dst = &LA[wave * (NLD * 512)];
#pragma unroll
    for (int v = 0; v < NLD; ++v)
      gload_lds16(src + v * 512, dst + v * 512);
  }
  __syncthreads();

  const int l15 = lane & 15, quad = lane >> 4;
  const int nn = n0 + wave * 16 + l15;
  const float bv = bias[nn];
  const unsigned short* wrow = WP + (long)nn * KS + quad * 8;
  const int sx = (l15 & 7) << 3;

  floatx4 acc0 = {0.f, 0.f, 0.f, 0.f};
  floatx4 acc1 = {0.f, 0.f, 0.f, 0.f};
#pragma unroll
  for (int kc = 0; kc < KS / 32; ++kc) {
    bf16x8 bfrag = *reinterpret_cast<const bf16x8*>(wrow + kc * 32);
    const int ko = (quad * 8 + kc * 32) ^ sx;
    bf16x8 a0 = *reinterpret_cast<const bf16x8*>(&LA[l15 * WROW + ko]);
    bf16x8 a1 = *reinterpret_cast<const bf16x8*>(&LA[(16 + l15) * WROW + ko]);
    acc0 = __builtin_amdgcn_mfma_f32_16x16x32_bf16(a0, bfrag, acc0, 0, 0, 0);
    acc1 = __builtin_amdgcn_mfma_f32_16x16x32_bf16(a1, bfrag, acc1, 0, 0, 0);
  }

  const int row = b * 256 + nn;
  float* yo = Yl + (long)row * 128;
  unsigned short* xb = (KWN != 0) ? (Xout + (long)b * BSTRN) : (unsigned short*)0;
#pragma unroll
  for (int half = 0; half < 2; ++half) {
    const floatx4& A = half ? acc1 : acc0;
#pragma unroll
    for (int r = 0; r < 4; ++r) {
      const int m = m0 + half * 16 + quad * 4 + r;
      if (m < Lout) {
        const float v = A[r] + bv;
        yo[m] = v;
        const unsigned short bf = f2bf(v);
        if constexpr (KWN == 2) {
          xb[m * 512 + ((2 * nn) ^ ((m & 7) << 3))] = bf;
          if (m >= 1) xb[(m - 1) * 512 + ((2 * nn + 1) ^ (((m - 1) & 7) << 3))] = bf;
        } else if constexpr (KWN == 3) {
          const int mh = m >> 1;
          if ((m & 1) == 0) {
            xb[mh * 768 + ((3 * nn) ^ ((mh & 7) << 3))] = bf;
            if (m >= 2) xb[(mh - 1) * 768 + ((3 * nn + 2) ^ (((mh - 1) & 7) << 3))] = bf;
          } else {
            xb[mh * 768 + ((3 * nn + 1) ^ ((mh & 7) << 3))] = bf;
          }
        }
      }
    }
  }
}

// ---- tail step: one conv layer fully inside LDS (same layout/K-order as conv_kernel)
template<int KW, int KWN, int LOUT>
__device__ __forceinline__ void tail_step(
    unsigned short* __restrict__ arena, const int inOff, const int outOff,
    const unsigned short* __restrict__ WP, const float* __restrict__ bias,
    float* __restrict__ Yl, int b, int tid)
{
  constexpr int KS = 256 * KW, WROW = KS;
  constexpr int MT = (LOUT + 15) / 16;          // 4 or 2 (always even here)
  const int wave = tid >> 6, lane = tid & 63, l15 = lane & 15, quad = lane >> 4;
  const int sx = (l15 & 7) << 3;

#pragma unroll
  for (int nt = 0; nt < 4; ++nt) {
    const int nn = nt * 64 + wave * 16 + l15;
    const unsigned short* wrow = WP + (long)nn * KS + quad * 8;
    const float bv = bias[nn];
    const int row = b * 256 + nn;
    float* yo = Yl + (long)row * 128;
#pragma unroll
    for (int mt = 0; mt < MT; mt += 2) {
      floatx4 acc0 = {0.f, 0.f, 0.f, 0.f};
      floatx4 acc1 = {0.f, 0.f, 0.f, 0.f};
#pragma unroll
      for (int kc = 0; kc < KS / 32; ++kc) {
        bf16x8 bfrag = *reinterpret_cast<const bf16x8*>(wrow + kc * 32);
        const int ko = (quad * 8 + kc * 32) ^ sx;
        bf16x8 a0 = *reinterpret_cast<const bf16x8*>(&arena[inOff + (mt * 16 + l15) * WROW + ko]);
        bf16x8 a1 = *reinterpret_cast<const bf16x8*>(&arena[inOff + ((mt + 1) * 16 + l15) * WROW + ko]);
        acc0 = __builtin_amdgcn_mfma_f32_16x16x32_bf16(a0, bfrag, acc0, 0, 0, 0);
        acc1 = __builtin_amdgcn_mfma_f32_16x16x32_bf16(a1, bfrag, acc1, 0, 0, 0);
      }
#pragma unroll
      for (int half = 0; half < 2; ++half) {
        const floatx4& A = half ? acc1 : acc0;
#pragma unroll
        for (int r = 0; r < 4; ++r) {
          const int m = (mt + half) * 16 + quad * 4 + r;
          if (m < LOUT) {
            const float v = A[r] + bv;
            yo[m] = v;
            const unsigned short bf = f2bf(v);
            if constexpr (KWN == 2) {
              arena[outOff + m * 512 + ((2 * nn) ^ ((m & 7) << 3))] = bf;
              if (m >= 1)
                arena[outOff + (m - 1) * 512 + ((2 * nn + 1) ^ (((m - 1) & 7) << 3))] = bf;
            } else if constexpr (KWN == 3) {
              const int mh = m >> 1;
              if ((m & 1) == 0) {
                arena[outOff + mh * 768 + ((3 * nn) ^ ((mh & 7) << 3))] = bf;
                if (m >= 2)
                  arena[outOff + (mh - 1) * 768 + ((3 * nn + 2) ^ (((mh - 1) & 7) << 3))] = bf;
              } else {
                arena[outOff + mh * 768 + ((3 * nn + 1) ^ ((mh & 7) << 3))] = bf;
              }
            }
          }
        }
      }
    }
  }
  __syncthreads();
}

// ---- tail kernel: layers 15..30 LDS-resident, one block per batch ----
#define R0 0
#define R1 43776
__global__ __launch_bounds__(256) void tail_kernel(
    const unsigned short* __restrict__ ws,
    const float* __restrict__ b2, const float* __restrict__ b3,
    float* __restrict__ Y)
{
  __shared__ unsigned short arena[76800];   // 153,600 B
  const int tid = threadIdx.x, b = blockIdx.x;
  const int wave = tid >> 6, lane = tid & 63;

  // stage carrier15 (rows 0..55 of k3 layout, 86016B) -> R0 (flat swizzled copy)
  {
    const unsigned short* src = ws + C15_E + (long)b * 49152;
#pragma unroll
    for (int it = 0; it < 21; ++it) {
      const int base = it * 256 + wave * 64;
      gload_lds16(src + (base + lane) * 8, &arena[base * 8]);
    }
  }
  __syncthreads();

  const unsigned short* wp2 = ws;
  const unsigned short* wp3 = ws + WP3_OFF;
  float* Yl = Y + (long)15 * 524288;

  tail_step<3,2,56>(arena, R0, R1, wp3,               b3,             Yl, b, tid); Yl += 524288;
  tail_step<2,2,55>(arena, R1, R0, wp2 + 15L*131072,  b2 + 15*256,    Yl, b, tid); Yl += 524288;
  tail_step<2,2,54>(arena, R0, R1, wp2 + 16L*131072,  b2 + 16*256,    Yl, b, tid); Yl += 524288;
  tail_step<2,2,53>(arena, R1, R0, wp2 + 17L*131072,  b2 + 17*256,    Yl, b, tid); Yl += 524288;
  tail_step<2,2,52>(arena, R0, R1, wp2 + 18L*131072,  b2 + 18*256,    Yl, b, tid); Yl += 524288;
  tail_step<2,2,51>(arena, R1, R0, wp2 + 19L*131072,  b2 + 19*256,    Yl, b, tid); Yl += 524288;
  tail_step<2,2,50>(arena, R0, R1, wp2 + 20L*131072,  b2 + 20*256,    Yl, b, tid); Yl += 524288;
  tail_step<2,3,49>(arena, R1, R0, wp2 + 21L*131072,  b2 + 21*256,    Yl, b, tid); Yl += 524288;
  tail_step<3,2,24>(arena, R0, R1, wp3 + 196608,      b3 + 256,       Yl, b, tid); Yl += 524288;
  tail_step<2,2,23>(arena, R1, R0, wp2 + 22L*131072,  b2 + 22*256,    Yl, b, tid); Yl += 524288;
  tail_step<2,2,22>(arena, R0, R1, wp2 + 23L*131072,  b2 + 23*256,    Yl, b, tid); Yl += 524288;
  tail_step<2,2,21>(arena, R1, R0, wp2 + 24L*131072,  b2 + 24*256,    Yl, b, tid); Yl += 524288;
  tail_step<2,2,20>(arena, R0, R1, wp2 + 25L*131072,  b2 + 25*256,    Yl, b, tid); Yl += 524288;
  tail_step<2,2,19>(arena, R1, R0, wp2 + 26L*131072,  b2 + 26*256,    Yl, b, tid); Yl += 524288;
  tail_step<2,2,18>(arena, R0, R1, wp2 + 27L*131072,  b2 + 27*256,    Yl, b, tid); Yl += 524288;
  tail_step<2,0,17>(arena, R1, R0, wp2 + 28L*131072,  b2 + 28*256,    Yl, b, tid);
}

// ---- assemble v4 (validated R7/R8) ----
__global__ __launch_bounds__(256) void assemble_kernel(
    float* __restrict__ out, const float* __restrict__ x,
    const unsigned short* __restrict__ tbl, const float* __restrict__ Y)
{
  __shared__ float S[32 * 65];
  const int bh = blockIdx.x;
  const int blk = bh >> 1, h = bh & 1;
  const int tid = threadIdx.x;

  ushort4v t4s[8];
  const unsigned short* tb = tbl + h * 8192;
#pragma unroll
  for (int it = 0; it < 8; ++it)
    t4s[it] = *reinterpret_cast<const ushort4v*>(tb + 4 * (it * 256 + tid));

#pragma unroll
  for (int p = 0; p < 8; ++p) {
    const int idx = p * 256 + tid;
    const int slot = idx >> 6, m = idx & 63;
    if (slot < 15) {
      const int mm = h * 64 + m;
      if (mm < 127 - slot) S[slot * 65 + m] = Y[(long)slot * 524288 + blk * 128 + mm];
    } else if (slot < 23) {
      if (m < 32) {
        const int mm = h * 32 + m;
        const int Lout = (slot == 15) ? 56 : (71 - slot);
        if (mm < Lout) S[slot * 65 + m] = Y[(long)slot * 524288 + blk * 128 + mm];
      }
    } else if (slot < 31) {
      if (m < 16) {
        const int mm = h * 16 + m;
        const int Lout = (slot == 23) ? 24 : (47 - slot);
        if (mm < Lout) S[slot * 65 + m] = Y[(long)slot * 524288 + blk * 128 + mm];
      }
    } else {
      S[31 * 65 + m] = x[blk * 128 + h * 64 + m];
    }
  }
  __syncthreads();

  const long obase = ((long)blk << 14) + ((long)h << 13);
#pragma unroll
  for (int it = 0; it < 8; ++it) {
    const int flat = it * 256 + tid;
    const ushort4v t4 = t4s[it];
    fvec4 v;
#pragma unroll
    for (int jj = 0; jj < 4; ++jj) {
      const unsigned short t = t4[jj];
      const int idx = (t == 0xFFFFu) ? 0 : (int)t;
      const float sv = S[idx];
      v[jj] = (t == 0xFFFFu) ? 0.f : sv;
    }
    *reinterpret_cast<fvec4*>(out + obase + 4 * flat) = v;
  }
}

extern "C" void kernel_launch(void* const* d_in, const int* in_sizes, int n_in,
                              void* d_out, int out_size, void* d_ws, size_t ws_size,
                              hipStream_t stream)
{
  const float* x  = (const float*)d_in[0];
  const float* w2 = (const float*)d_in[1];
  const float* b2 = (const float*)d_in[2];
  const float* w3 = (const float*)d_in[3];
  const float* b3 = (const float*)d_in[4];
  float* out = (float*)d_out;
  unsigned short* ws = (unsigned short*)d_ws;
  unsigned short* tbl = ws + TBL_E;
  float* Y = (float*)((char*)d_ws + Y_B);

  prep_kernel<<<4608, 256, 0, stream>>>(w2, w3, x, ws);
  tbl_kernel<<<64, 256, 0, stream>>>(tbl);

  // layers 0..14 (all KW=2); l14 writes the k3 carrier for the tail
  long cin = XC0_E;
  int Lin = 128;
  for (int l = 0; l < 15; ++l) {
    const int Lout = Lin - 1;
    const long cnext = cin + (long)16 * 65536;
    const unsigned short* WPt = ws + (long)l * 131072;
    const float* bt = b2 + l * 256;
    dim3 grid((Lout + 31) / 32, 4, 16);
    float* Yl = Y + (long)l * 524288;
    if (l == 14)
      conv_kernel<2,3><<<grid, 256, 0, stream>>>(ws + cin, ws + cnext, WPt, bt, Yl, Lout);
    else
      conv_kernel<2,2><<<grid, 256, 0, stream>>>(ws + cin, ws + cnext, WPt, bt, Yl, Lout);
    cin = cnext;
    Lin = Lout;
  }

  // layers 15..30 in one LDS-resident kernel (one block per batch)
  tail_kernel<<<16, 256, 0, stream>>>(ws, b2, b3, Y);

  assemble_kernel<<<8192, 256, 0, stream>>>(out, x, tbl, Y);
}

// Round 10
// 686.818 us; speedup vs baseline: 1.1640x; 1.1640x over previous
//
#include <hip/hip_runtime.h>

// ---- types ----
typedef __bf16 bf16x8 __attribute__((ext_vector_type(8)));
typedef float  floatx4 __attribute__((ext_vector_type(4)));
typedef float  fvec4  __attribute__((ext_vector_type(4)));
typedef unsigned short ushort4v __attribute__((ext_vector_type(4)));

__device__ __forceinline__ unsigned short f2bf(float f) {
  unsigned int u = __float_as_uint(f);
  u = u + 0x7FFFu + ((u >> 16) & 1u);   // RNE
  return (unsigned short)(u >> 16);
}

__device__ __forceinline__ void gload_lds16(const unsigned short* g, unsigned short* l) {
  __builtin_amdgcn_global_load_lds(
      (const __attribute__((address_space(1))) unsigned int*)(g),
      (__attribute__((address_space(3))) unsigned int*)(l), 16, 0, 0);
}

// ws layout (u16-elem offsets unless noted):
//   0        : WP2 bf16 [29][256][512]
//   3801088  : WP3 bf16 [2][256][768]
//   8388608  : carriers l=0..15 (k-major swizzled, as R8):
//              l0..14: 16 x 65536 u16 (KW2); carrier15: 16 x 49152 u16 (KW3).
//   90 MiB   : tbl u16 [2][64][128] (assemble)
//   96 MiB   : Y fp32 [31][16*256][128]
#define WP3_OFF   3801088
#define XC0_E     8388608
#define C15_E     24117248
#define TBL_E     47185920
#define Y_B       100663296

// ---- prep: bf16 weight copies + X0 carrier (k-major swizzled) ----
__global__ __launch_bounds__(256) void prep_kernel(
    const float* __restrict__ w2, const float* __restrict__ w3,
    const float* __restrict__ x, unsigned short* __restrict__ ws)
{
  int g = blockIdx.x * 256 + threadIdx.x;          // 0 .. 1179647
  if (g < 1048576) {
    const float* src; unsigned short* dst;
    if (g < 950272) { src = w2; dst = ws; }
    else            { g -= 950272; src = w3; dst = ws + WP3_OFF; }
    fvec4 v = *reinterpret_cast<const fvec4*>(src + 4 * g);
    ushort4v o;
    o[0] = f2bf(v[0]); o[1] = f2bf(v[1]); o[2] = f2bf(v[2]); o[3] = f2bf(v[3]);
    *reinterpret_cast<ushort4v*>(dst + 4 * g) = o;
  } else {
    const int h = g - 1048576;                     // 0..131071 over x float4 groups
    const long f = (long)4 * h;
    const int bb = (int)(f >> 15);
    const int i  = (int)((f >> 7) & 255);
    const int p0 = (int)(f & 127);
    fvec4 v = *reinterpret_cast<const fvec4*>(x + f);
    unsigned short* xb = ws + XC0_E + (long)bb * 65536;
#pragma unroll
    for (int j = 0; j < 4; ++j) {
      const int p = p0 + j;
      const unsigned short bf = f2bf(v[j]);
      xb[p * 512 + ((2 * i) ^ ((p & 7) << 3))] = bf;
      if (p >= 1) xb[(p - 1) * 512 + ((2 * i + 1) ^ (((p - 1) & 7) << 3))] = bf;
    }
  }
}

// ---- per-half assemble index table (validated R7/R8) ----
__global__ __launch_bounds__(256) void tbl_kernel(unsigned short* __restrict__ tbl)
{
  const int g = blockIdx.x * 256 + threadIdx.x;   // 0..16383
  const int h = g >> 13, rl = (g >> 7) & 63, c = g & 127;
  const int r = h * 64 + rl, d = c - r;
  unsigned short v = 0xFFFFu;
  if (d == 0) v = (unsigned short)(31 * 65 + rl);
  else if (d >= 1 && d <= 15) v = (unsigned short)((d - 1) * 65 + rl);
  else if (d >= 17 && d <= 31 && (d & 1) == 1 && (r & 1) == 0)
    v = (unsigned short)((15 + ((d - 17) >> 1)) * 65 + (rl >> 1));
  else if (d >= 35 && d <= 63 && (d & 3) == 3 && (r & 3) == 0)
    v = (unsigned short)((23 + ((d - 35) >> 2)) * 65 + (rl >> 2));
  tbl[g] = v;
}

// ---- conv layer (validated R8): k-major swizzled carriers, async staging ----
template<int KW, int KWN>
__global__ __launch_bounds__(256) void conv_kernel(
    const unsigned short* __restrict__ Xin, unsigned short* __restrict__ Xout,
    const unsigned short* __restrict__ WP, const float* __restrict__ bias,
    float* __restrict__ Yl, int Lout)
{
  constexpr int WROW  = 256 * KW;
  constexpr int BSTR  = (KW == 2) ? 65536 : 49152;
  constexpr int BSTRN = (KWN == 3) ? 49152 : 65536;
  constexpr int KS    = 256 * KW;
  constexpr int NLD   = (KW == 2) ? 8 : 12;
  __shared__ unsigned short LA[32 * WROW];

  const int tid = threadIdx.x, wave = tid >> 6, lane = tid & 63;
  const int b = blockIdx.z, m0 = blockIdx.x * 32, n0 = blockIdx.y * 64;
  {
    const unsigned short* src = Xin + (long)b * BSTR + (long)m0 * WROW
                              + wave * (NLD * 512) + lane * 8;
    unsigned short* dst = &LA[wave * (NLD * 512)];
#pragma unroll
    for (int v = 0; v < NLD; ++v)
      gload_lds16(src + v * 512, dst + v * 512);
  }
  __syncthreads();

  const int l15 = lane & 15, quad = lane >> 4;
  const int nn = n0 + wave * 16 + l15;
  const float bv = bias[nn];
  const unsigned short* wrow = WP + (long)nn * KS + quad * 8;
  const int sx = (l15 & 7) << 3;

  floatx4 acc0 = {0.f, 0.f, 0.f, 0.f};
  floatx4 acc1 = {0.f, 0.f, 0.f, 0.f};
#pragma unroll
  for (int kc = 0; kc < KS / 32; ++kc) {
    bf16x8 bfrag = *reinterpret_cast<const bf16x8*>(wrow + kc * 32);
    const int ko = (quad * 8 + kc * 32) ^ sx;
    bf16x8 a0 = *reinterpret_cast<const bf16x8*>(&LA[l15 * WROW + ko]);
    bf16x8 a1 = *reinterpret_cast<const bf16x8*>(&LA[(16 + l15) * WROW + ko]);
    acc0 = __builtin_amdgcn_mfma_f32_16x16x32_bf16(a0, bfrag, acc0, 0, 0, 0);
    acc1 = __builtin_amdgcn_mfma_f32_16x16x32_bf16(a1, bfrag, acc1, 0, 0, 0);
  }

  const int row = b * 256 + nn;
  float* yo = Yl + (long)row * 128;
  unsigned short* xb = (KWN != 0) ? (Xout + (long)b * BSTRN) : (unsigned short*)0;
#pragma unroll
  for (int half = 0; half < 2; ++half) {
    const floatx4& A = half ? acc1 : acc0;
#pragma unroll
    for (int r = 0; r < 4; ++r) {
      const int m = m0 + half * 16 + quad * 4 + r;
      if (m < Lout) {
        const float v = A[r] + bv;
        yo[m] = v;
        const unsigned short bf = f2bf(v);
        if constexpr (KWN == 2) {
          xb[m * 512 + ((2 * nn) ^ ((m & 7) << 3))] = bf;
          if (m >= 1) xb[(m - 1) * 512 + ((2 * nn + 1) ^ (((m - 1) & 7) << 3))] = bf;
        } else if constexpr (KWN == 3) {
          const int mh = m >> 1;
          if ((m & 1) == 0) {
            xb[mh * 768 + ((3 * nn) ^ ((mh & 7) << 3))] = bf;
            if (m >= 2) xb[(mh - 1) * 768 + ((3 * nn + 2) ^ (((mh - 1) & 7) << 3))] = bf;
          } else {
            xb[mh * 768 + ((3 * nn + 1) ^ ((mh & 7) << 3))] = bf;
          }
        }
      }
    }
  }
}

// ---- tail step v2: one conv layer in LDS; wave owns 16 channels (16 waves = 256).
// Same layout/K-order/write formulas as R9 (bit-identical); only the wave->work
// mapping changed (R9's nt loop -> wave index).
template<int KW, int KWN, int LOUT>
__device__ __forceinline__ void tail_step(
    unsigned short* __restrict__ arena, const int inOff, const int outOff,
    const unsigned short* __restrict__ WP, const float* __restrict__ bias,
    float* __restrict__ Yl, int b, int tid)
{
  constexpr int KS = 256 * KW, WROW = KS;
  constexpr int MT = (LOUT + 15) / 16;          // 4 or 2 (always even here)
  const int wave = tid >> 6, lane = tid & 63, l15 = lane & 15, quad = lane >> 4;
  const int sx = (l15 & 7) << 3;
  const int nn = wave * 16 + l15;
  const unsigned short* wrow = WP + (long)nn * KS + quad * 8;
  const float bv = bias[nn];
  const int row = b * 256 + nn;
  float* yo = Yl + (long)row * 128;

#pragma unroll
  for (int mt = 0; mt < MT; mt += 2) {
    floatx4 acc0 = {0.f, 0.f, 0.f, 0.f};
    floatx4 acc1 = {0.f, 0.f, 0.f, 0.f};
#pragma unroll
    for (int kc = 0; kc < KS / 32; ++kc) {
      bf16x8 bfrag = *reinterpret_cast<const bf16x8*>(wrow + kc * 32);
      const int ko = (quad * 8 + kc * 32) ^ sx;
      bf16x8 a0 = *reinterpret_cast<const bf16x8*>(&arena[inOff + (mt * 16 + l15) * WROW + ko]);
      bf16x8 a1 = *reinterpret_cast<const bf16x8*>(&arena[inOff + ((mt + 1) * 16 + l15) * WROW + ko]);
      acc0 = __builtin_amdgcn_mfma_f32_16x16x32_bf16(a0, bfrag, acc0, 0, 0, 0);
      acc1 = __builtin_amdgcn_mfma_f32_16x16x32_bf16(a1, bfrag, acc1, 0, 0, 0);
    }
#pragma unroll
    for (int half = 0; half < 2; ++half) {
      const floatx4& A = half ? acc1 : acc0;
#pragma unroll
      for (int r = 0; r < 4; ++r) {
        const int m = (mt + half) * 16 + quad * 4 + r;
        if (m < LOUT) {
          const float v = A[r] + bv;
          yo[m] = v;
          const unsigned short bf = f2bf(v);
          if constexpr (KWN == 2) {
            arena[outOff + m * 512 + ((2 * nn) ^ ((m & 7) << 3))] = bf;
            if (m >= 1)
              arena[outOff + (m - 1) * 512 + ((2 * nn + 1) ^ (((m - 1) & 7) << 3))] = bf;
          } else if constexpr (KWN == 3) {
            const int mh = m >> 1;
            if ((m & 1) == 0) {
              arena[outOff + mh * 768 + ((3 * nn) ^ ((mh & 7) << 3))] = bf;
              if (m >= 2)
                arena[outOff + (mh - 1) * 768 + ((3 * nn + 2) ^ (((mh - 1) & 7) << 3))] = bf;
            } else {
              arena[outOff + mh * 768 + ((3 * nn + 1) ^ ((mh & 7) << 3))] = bf;
            }
          }
        }
      }
    }
  }
  __syncthreads();
}

// ---- tail kernel v2: layers 15..30 LDS-resident, 1024 threads (16 waves) ----
#define R0 0
#define R1 43776
__global__ __launch_bounds__(1024, 1) void tail_kernel(
    const unsigned short* __restrict__ ws,
    const float* __restrict__ b2, const float* __restrict__ b3,
    float* __restrict__ Y)
{
  __shared__ unsigned short arena[76800];   // 153,600 B
  const int tid = threadIdx.x, b = blockIdx.x;
  const int wave = tid >> 6, lane = tid & 63;

  // stage carrier15 (56 rows x 768 u16 = 86016B = 5376 x 16B) -> R0 (flat copy)
  {
    const unsigned short* src = ws + C15_E + (long)b * 49152;
#pragma unroll
    for (int it = 0; it < 6; ++it) {
      const int base = it * 1024 + wave * 64;      // wave-uniform
      if (base < 5376)
        gload_lds16(src + (base + lane) * 8, &arena[base * 8]);
    }
  }
  __syncthreads();

  const unsigned short* wp2 = ws;
  const unsigned short* wp3 = ws + WP3_OFF;
  float* Yl = Y + (long)15 * 524288;

  tail_step<3,2,56>(arena, R0, R1, wp3,               b3,             Yl, b, tid); Yl += 524288;
  tail_step<2,2,55>(arena, R1, R0, wp2 + 15L*131072,  b2 + 15*256,    Yl, b, tid); Yl += 524288;
  tail_step<2,2,54>(arena, R0, R1, wp2 + 16L*131072,  b2 + 16*256,    Yl, b, tid); Yl += 524288;
  tail_step<2,2,53>(arena, R1, R0, wp2 + 17L*131072,  b2 + 17*256,    Yl, b, tid); Yl += 524288;
  tail_step<2,2,52>(arena, R0, R1, wp2 + 18L*131072,  b2 + 18*256,    Yl, b, tid); Yl += 524288;
  tail_step<2,2,51>(arena, R1, R0, wp2 + 19L*131072,  b2 + 19*256,    Yl, b, tid); Yl += 524288;
  tail_step<2,2,50>(arena, R0, R1, wp2 + 20L*131072,  b2 + 20*256,    Yl, b, tid); Yl += 524288;
  tail_step<2,3,49>(arena, R1, R0, wp2 + 21L*131072,  b2 + 21*256,    Yl, b, tid); Yl += 524288;
  tail_step<3,2,24>(arena, R0, R1, wp3 + 196608,      b3 + 256,       Yl, b, tid); Yl += 524288;
  tail_step<2,2,23>(arena, R1, R0, wp2 + 22L*131072,  b2 + 22*256,    Yl, b, tid); Yl += 524288;
  tail_step<2,2,22>(arena, R0, R1, wp2 + 23L*131072,  b2 + 23*256,    Yl, b, tid); Yl += 524288;
  tail_step<2,2,21>(arena, R1, R0, wp2 + 24L*131072,  b2 + 24*256,    Yl, b, tid); Yl += 524288;
  tail_step<2,2,20>(arena, R0, R1, wp2 + 25L*131072,  b2 + 25*256,    Yl, b, tid); Yl += 524288;
  tail_step<2,2,19>(arena, R1, R0, wp2 + 26L*131072,  b2 + 26*256,    Yl, b, tid); Yl += 524288;
  tail_step<2,2,18>(arena, R0, R1, wp2 + 27L*131072,  b2 + 27*256,    Yl, b, tid); Yl += 524288;
  tail_step<2,0,17>(arena, R1, R0, wp2 + 28L*131072,  b2 + 28*256,    Yl, b, tid);
}

// ---- assemble v4 (validated R7/R8) ----
__global__ __launch_bounds__(256) void assemble_kernel(
    float* __restrict__ out, const float* __restrict__ x,
    const unsigned short* __restrict__ tbl, const float* __restrict__ Y)
{
  __shared__ float S[32 * 65];
  const int bh = blockIdx.x;
  const int blk = bh >> 1, h = bh & 1;
  const int tid = threadIdx.x;

  ushort4v t4s[8];
  const unsigned short* tb = tbl + h * 8192;
#pragma unroll
  for (int it = 0; it < 8; ++it)
    t4s[it] = *reinterpret_cast<const ushort4v*>(tb + 4 * (it * 256 + tid));

#pragma unroll
  for (int p = 0; p < 8; ++p) {
    const int idx = p * 256 + tid;
    const int slot = idx >> 6, m = idx & 63;
    if (slot < 15) {
      const int mm = h * 64 + m;
      if (mm < 127 - slot) S[slot * 65 + m] = Y[(long)slot * 524288 + blk * 128 + mm];
    } else if (slot < 23) {
      if (m < 32) {
        const int mm = h * 32 + m;
        const int Lout = (slot == 15) ? 56 : (71 - slot);
        if (mm < Lout) S[slot * 65 + m] = Y[(long)slot * 524288 + blk * 128 + mm];
      }
    } else if (slot < 31) {
      if (m < 16) {
        const int mm = h * 16 + m;
        const int Lout = (slot == 23) ? 24 : (47 - slot);
        if (mm < Lout) S[slot * 65 + m] = Y[(long)slot * 524288 + blk * 128 + mm];
      }
    } else {
      S[31 * 65 + m] = x[blk * 128 + h * 64 + m];
    }
  }
  __syncthreads();

  const long obase = ((long)blk << 14) + ((long)h << 13);
#pragma unroll
  for (int it = 0; it < 8; ++it) {
    const int flat = it * 256 + tid;
    const ushort4v t4 = t4s[it];
    fvec4 v;
#pragma unroll
    for (int jj = 0; jj < 4; ++jj) {
      const unsigned short t = t4[jj];
      const int idx = (t == 0xFFFFu) ? 0 : (int)t;
      const float sv = S[idx];
      v[jj] = (t == 0xFFFFu) ? 0.f : sv;
    }
    *reinterpret_cast<fvec4*>(out + obase + 4 * flat) = v;
  }
}

extern "C" void kernel_launch(void* const* d_in, const int* in_sizes, int n_in,
                              void* d_out, int out_size, void* d_ws, size_t ws_size,
                              hipStream_t stream)
{
  const float* x  = (const float*)d_in[0];
  const float* w2 = (const float*)d_in[1];
  const float* b2 = (const float*)d_in[2];
  const float* w3 = (const float*)d_in[3];
  const float* b3 = (const float*)d_in[4];
  float* out = (float*)d_out;
  unsigned short* ws = (unsigned short*)d_ws;
  unsigned short* tbl = ws + TBL_E;
  float* Y = (float*)((char*)d_ws + Y_B);

  prep_kernel<<<4608, 256, 0, stream>>>(w2, w3, x, ws);
  tbl_kernel<<<64, 256, 0, stream>>>(tbl);

  // layers 0..14 (all KW=2); l14 writes the k3 carrier for the tail
  long cin = XC0_E;
  int Lin = 128;
  for (int l = 0; l < 15; ++l) {
    const int Lout = Lin - 1;
    const long cnext = cin + (long)16 * 65536;
    const unsigned short* WPt = ws + (long)l * 131072;
    const float* bt = b2 + l * 256;
    dim3 grid((Lout + 31) / 32, 4, 16);
    float* Yl = Y + (long)l * 524288;
    if (l == 14)
      conv_kernel<2,3><<<grid, 256, 0, stream>>>(ws + cin, ws + cnext, WPt, bt, Yl, Lout);
    else
      conv_kernel<2,2><<<grid, 256, 0, stream>>>(ws + cin, ws + cnext, WPt, bt, Yl, Lout);
    cin = cnext;
    Lin = Lout;
  }

  // layers 15..30 in one LDS-resident kernel (16 waves per block, one per batch)
  tail_kernel<<<16, 1024, 0, stream>>>(ws, b2, b3, Y);

  assemble_kernel<<<8192, 256, 0, stream>>>(out, x, tbl, Y);
}